// Round 2
// baseline (269.950 us; speedup 1.0000x reference)
//
#include <hip/hip_runtime.h>
#include <hip/hip_bf16.h>
#include <math.h>

#define C_CH 8
#define H_DIM 512
#define BS 32768            // B*S
#define K_DIM 4096          // C*H
#define EPS 1e-5f

#define TM 64
#define TK 32
#define NKT (K_DIM / TK)    // 128 K-tiles
#define GRP 4               // k-tiles per barrier group
#define NGRP (NKT / GRP)    // 32 groups
#define AELEMS (TM * TK * GRP)   // 8192 bf16 per group buffer (16 KB)

typedef __bf16 bf16x8 __attribute__((ext_vector_type(8)));
typedef float  floatx16 __attribute__((ext_vector_type(16)));

// tanh-form GELU, exp2-folded: gelu(v) ~= v * sigmoid(1.5957691*(v+0.044715 v^3))
// constants pre-multiplied by log2(e); max abs dev from exact erf-gelu ~3e-4.
__device__ __forceinline__ float gelu_fast(float v) {
    float x2 = v * fmaf(v * v, 0.102943215f, 2.30220815f);   // x*log2e
    float e = __builtin_amdgcn_exp2f(-x2);
    return v * __builtin_amdgcn_rcpf(1.0f + e);
}

// Prep kernel, grid = 1024 + 8 blocks x 256 threads.
// Blocks [0,1024): mod_w fp32 [512][4096] -> bf16 workspace in 32x32x16 MFMA
//   B-fragment chunk layout: chunk(kh 0..255, n32 0..15) of 64 lanes x 16B;
//   lane l holds B[col = n32*32 + (l&31)][k = kh*16 + (l>>5)*8 + i], i=0..7.
// Blocks [1024,1032): per-channel encoder-LN fold (c = blockIdx-1024):
//   Wf[c][j] = gamma*(w - mean(w)), Bf[c][j] = gamma*(b - mean(b)),
//   st[c] = {var_w, 2*cov_wb, var_b} so the fused kernel's per-row work is
//   q = rsqrt(x^2 vw + x*2cwb + vb + eps), p = x*q, and
//   A[row][c*512+j] = gelu(p*Wf + q*Bf + enc_beta).
__global__ __launch_bounds__(256) void prep_kernel(
    const float* __restrict__ w, __bf16* __restrict__ o,
    const float* __restrict__ enc_w, const float* __restrict__ enc_b,
    const float* __restrict__ enc_gamma,
    float* __restrict__ Wf, float* __restrict__ Bf, float* __restrict__ st)
{
    __shared__ float red[4][5];
    if (blockIdx.x < 1024) {
        int gtid  = blockIdx.x * 256 + threadIdx.x;   // 0..262143
        int lane  = gtid & 63;
        int chunk = gtid >> 6;                        // 0..4095
        int kh    = chunk >> 4;                       // 0..255
        int n32   = chunk & 15;                       // 0..15
        int col   = n32 * 32 + (lane & 31);
        int k     = kh * 16 + (lane >> 5) * 8;
        const float* src = w + (size_t)col * K_DIM + k;
        float4 a = *(const float4*)src;
        float4 b = *(const float4*)(src + 4);
        bf16x8 h;
        h[0] = (__bf16)a.x; h[1] = (__bf16)a.y; h[2] = (__bf16)a.z; h[3] = (__bf16)a.w;
        h[4] = (__bf16)b.x; h[5] = (__bf16)b.y; h[6] = (__bf16)b.z; h[7] = (__bf16)b.w;
        *(bf16x8*)(o + (size_t)gtid * 8) = h;
    } else {
        const int c = blockIdx.x - 1024;              // 0..7
        const int t = threadIdx.x;                    // 0..255
        const float* wp = enc_w + c * H_DIM;
        const float* bp = enc_b + c * H_DIM;
        const float* gp = enc_gamma + c * H_DIM;
        float w0 = wp[t], w1 = wp[t + 256];
        float b0 = bp[t], b1 = bp[t + 256];
        float sw  = w0 + w1;
        float sb  = b0 + b1;
        float sww = fmaf(w0, w0, w1 * w1);
        float sbb = fmaf(b0, b0, b1 * b1);
        float swb = fmaf(w0, b0, w1 * b1);
        #pragma unroll
        for (int off = 32; off; off >>= 1) {
            sw  += __shfl_xor(sw,  off);
            sb  += __shfl_xor(sb,  off);
            sww += __shfl_xor(sww, off);
            sbb += __shfl_xor(sbb, off);
            swb += __shfl_xor(swb, off);
        }
        int wv = t >> 6, ln = t & 63;
        if (ln == 0) {
            red[wv][0] = sw;  red[wv][1] = sb;  red[wv][2] = sww;
            red[wv][3] = sbb; red[wv][4] = swb;
        }
        __syncthreads();
        float tsw  = red[0][0] + red[1][0] + red[2][0] + red[3][0];
        float tsb  = red[0][1] + red[1][1] + red[2][1] + red[3][1];
        float tsww = red[0][2] + red[1][2] + red[2][2] + red[3][2];
        float tsbb = red[0][3] + red[1][3] + red[2][3] + red[3][3];
        float tswb = red[0][4] + red[1][4] + red[2][4] + red[3][4];
        const float inv = 1.0f / (float)H_DIM;
        float mw = tsw * inv, mb = tsb * inv;
        if (t == 0) {
            st[c * 4 + 0] = tsww * inv - mw * mw;           // var_w
            st[c * 4 + 1] = 2.0f * (tswb * inv - mw * mb);  // 2*cov
            st[c * 4 + 2] = tsbb * inv - mb * mb;           // var_b
        }
        float g0 = gp[t], g1 = gp[t + 256];
        Wf[c * H_DIM + t]       = g0 * (w0 - mw);
        Wf[c * H_DIM + t + 256] = g1 * (w1 - mw);
        Bf[c * H_DIM + t]       = g0 * (b0 - mb);
        Bf[c * H_DIM + t + 256] = g1 * (b1 - mb);
    }
}

// Fused: analytic enc-LN -> gelu -> GEMM(mod_w^T) -> +mod_b -> LayerNorm -> gelu.
// 512 threads / 8 waves, wave-tile 64x64 = 2x2 of 32x32 MFMA tiles (32x32x16).
// One barrier per 4 K-tiles. A staged slot-wise: each thread computes 8 elems
// per slot, 2 slots/group, one ds_write_b128 each; all LDS chunk accesses are
// contiguous 1KB (16B/lane linear = bank-conflict-free). B frags stream
// global(L2)->VGPR with P/Q rotation. s_setprio(1) around MFMA clusters.
template <int USE_WS>
__global__ __launch_bounds__(512, 4) void fused_gemm_kernel(
    const float* __restrict__ x,
    const float* __restrict__ enc_w,
    const float* __restrict__ enc_b,
    const float* __restrict__ enc_gamma,
    const float* __restrict__ enc_beta,
    const float* __restrict__ mod_w,      // fp32 fallback
    const __bf16* __restrict__ Wb,        // bf16 frag-layout (workspace)
    const float* __restrict__ Wf,         // folded gamma*(w-mw)   (workspace)
    const float* __restrict__ Bf,         // folded gamma*(b-mb)   (workspace)
    const float* __restrict__ st,         // per-channel {vw,2cwb,vb} (workspace)
    const float* __restrict__ mod_b,
    const float* __restrict__ mod_gamma,
    const float* __restrict__ mod_beta,
    float* __restrict__ out)
{
    __shared__ float stats[C_CH][5];            // legacy path only
    __shared__ float pS[C_CH][TM];
    __shared__ float qS[C_CH][TM];
    __shared__ float rS[C_CH][TM];              // legacy path only
    __shared__ __align__(16) __bf16 Als[2 * AELEMS];   // 32 KB
    __shared__ float redS[TM][8];
    __shared__ float redQ[TM][8];
    __shared__ float muS[TM];
    __shared__ float invS[TM];

    const int tid  = threadIdx.x;
    const int wave = tid >> 6;        // 0..7
    const int lane = tid & 63;
    const int row0 = blockIdx.x * TM;

    if (USE_WS) {
        // ---- per-(channel,row) p,q from precomputed channel stats ----
        int c = wave;                 // 512 threads == 8 channels x 64 rows
        int m = lane;
        float xv = x[c * BS + row0 + m];
        float vw = st[c * 4 + 0], cwb2 = st[c * 4 + 1], vb = st[c * 4 + 2];
        float q = rsqrtf(fmaf(xv, fmaf(xv, vw, cwb2), vb) + EPS);
        pS[c][m] = xv * q;
        qS[c][m] = q;
    } else {
        // ---- legacy: in-kernel stats, then p,q,r ----
        {
            const int c = wave;
            float sw = 0.f, sb = 0.f, sww = 0.f, sbb = 0.f, swb = 0.f;
            for (int j = lane; j < H_DIM; j += 64) {
                float w = enc_w[c * H_DIM + j];
                float b = enc_b[c * H_DIM + j];
                sw += w; sb += b;
                sww = fmaf(w, w, sww);
                sbb = fmaf(b, b, sbb);
                swb = fmaf(w, b, swb);
            }
            #pragma unroll
            for (int off = 32; off; off >>= 1) {
                sw  += __shfl_xor(sw,  off);
                sb  += __shfl_xor(sb,  off);
                sww += __shfl_xor(sww, off);
                sbb += __shfl_xor(sbb, off);
                swb += __shfl_xor(swb, off);
            }
            if (lane == 0) {
                const float inv = 1.0f / (float)H_DIM;
                float mw = sw * inv, mb = sb * inv;
                stats[c][0] = mw;
                stats[c][1] = mb;
                stats[c][2] = sww * inv - mw * mw;
                stats[c][3] = sbb * inv - mb * mb;
                stats[c][4] = swb * inv - mw * mb;
            }
        }
        __syncthreads();
        {
            int c = wave;
            int m = lane;
            float xv = x[c * BS + row0 + m];
            float mw = stats[c][0], mb = stats[c][1];
            float vw = stats[c][2], vb = stats[c][3], cwb = stats[c][4];
            float var = fmaf(xv, fmaf(xv, vw, 2.0f * cwb), vb);
            float q = rsqrtf(var + EPS);
            float p = xv * q;
            pS[c][m] = p;
            qS[c][m] = q;
            rS[c][m] = -fmaf(p, mw, q * mb);
        }
    }
    __syncthreads();

    const int wn = wave;             // wave tile: 64 rows x 64 cols

    // A-slot decomposition: thread t owns lane-slot t (and t+512) of each
    // group's 16 chunks. chunk cg = sub*4 + q, q = kh*2 + mt; within chunk
    // lane sl holds A[row = mt*32 + (sl&31)][k = kt*32 + kh*16 + (sl>>5)*8 + i].
    const int scg   = tid >> 6;      // 0..7  (slot2 adds +8 -> sub+2, same q)
    const int sq    = scg & 3;
    const int skh   = sq >> 1;
    const int smt   = sq & 1;
    const int sl    = tid & 63;
    const int skoff = skh * 16 + (sl >> 5) * 8;
    const int arow  = smt * 32 + (sl & 31);
    const int ssub0 = scg >> 2;      // 0..1; slot2 sub = ssub0 + 2
    const int sdst0 = (sq * 512) + sl * 8;   // + sub*2048 at use site

    floatx16 acc[2][2];
    #pragma unroll
    for (int i = 0; i < 2; ++i)
        #pragma unroll
        for (int j = 0; j < 2; ++j)
            #pragma unroll
            for (int r = 0; r < 16; ++r)
                acc[i][j][r] = 0.f;

    // ---- A-stage (folded): v = p*Wf + q*Bf + beta; gelu; one 16B slot ----
    auto stageSlot = [&](int g1, int which, __bf16* dstbuf, float p, float q) {
        const int sub = ssub0 + which * 2;
        const int k0  = (g1 * GRP + sub) * TK + skoff;   // absolute k 0..4095
        float4 w0 = *(const float4*)(Wf + k0);
        float4 w1 = *(const float4*)(Wf + k0 + 4);
        float4 b0 = *(const float4*)(Bf + k0);
        float4 b1 = *(const float4*)(Bf + k0 + 4);
        float4 e0 = *(const float4*)(enc_beta + k0);
        float4 e1 = *(const float4*)(enc_beta + k0 + 4);
        float fw[8] = {w0.x, w0.y, w0.z, w0.w, w1.x, w1.y, w1.z, w1.w};
        float fb[8] = {b0.x, b0.y, b0.z, b0.w, b1.x, b1.y, b1.z, b1.w};
        float fe[8] = {e0.x, e0.y, e0.z, e0.w, e1.x, e1.y, e1.z, e1.w};
        bf16x8 hv;
        #pragma unroll
        for (int i = 0; i < 8; ++i) {
            float v = fmaf(p, fw[i], fmaf(q, fb[i], fe[i]));
            hv[i] = (__bf16)gelu_fast(v);
        }
        *(bf16x8*)(dstbuf + sub * 2048 + sdst0) = hv;
    };

    // ---- legacy A-stage: raw params + r term ----
    auto stageSlotL = [&](int g1, int which, __bf16* dstbuf,
                          float p, float q, float r) {
        const int sub = ssub0 + which * 2;
        const int k0  = (g1 * GRP + sub) * TK + skoff;
        float4 w0 = *(const float4*)(enc_w + k0);
        float4 w1 = *(const float4*)(enc_w + k0 + 4);
        float4 b0 = *(const float4*)(enc_b + k0);
        float4 b1 = *(const float4*)(enc_b + k0 + 4);
        float4 g0 = *(const float4*)(enc_gamma + k0);
        float4 g1v = *(const float4*)(enc_gamma + k0 + 4);
        float4 e0 = *(const float4*)(enc_beta + k0);
        float4 e1 = *(const float4*)(enc_beta + k0 + 4);
        float fw[8] = {w0.x, w0.y, w0.z, w0.w, w1.x, w1.y, w1.z, w1.w};
        float fb[8] = {b0.x, b0.y, b0.z, b0.w, b1.x, b1.y, b1.z, b1.w};
        float fg[8] = {g0.x, g0.y, g0.z, g0.w, g1v.x, g1v.y, g1v.z, g1v.w};
        float fe[8] = {e0.x, e0.y, e0.z, e0.w, e1.x, e1.y, e1.z, e1.w};
        bf16x8 hv;
        #pragma unroll
        for (int i = 0; i < 8; ++i) {
            float t = fmaf(p, fw[i], fmaf(q, fb[i], r));
            float v = fmaf(t, fg[i], fe[i]);
            hv[i] = (__bf16)gelu_fast(v);
        }
        *(bf16x8*)(dstbuf + sub * 2048 + sdst0) = hv;
    };

    // ---- B-frag loader: 2 frags (nt=0,1), one kh half of one k-tile ----
    const __bf16* baseB = Wb + (size_t)(wn * 128 + lane) * 8;
    auto loadB = [&](int kt, int half, bf16x8* dst) {
        if (USE_WS) {
            const __bf16* bp = baseB + (size_t)(2 * kt + half) * 8192;
            dst[0] = *(const bf16x8*)bp;
            dst[1] = *(const bf16x8*)(bp + 512);
        } else {
            const int k = (2 * kt + half) * 16 + (lane >> 5) * 8;
            #pragma unroll
            for (int nt = 0; nt < 2; ++nt) {
                int col = (wn * 2 + nt) * 32 + (lane & 31);
                const float* src = mod_w + (size_t)col * K_DIM + k;
                float4 a = *(const float4*)src;
                float4 b = *(const float4*)(src + 4);
                bf16x8 h;
                h[0] = (__bf16)a.x; h[1] = (__bf16)a.y; h[2] = (__bf16)a.z; h[3] = (__bf16)a.w;
                h[4] = (__bf16)b.x; h[5] = (__bf16)b.y; h[6] = (__bf16)b.z; h[7] = (__bf16)b.w;
                dst[nt] = h;
            }
        }
    };

    bf16x8 bfrP[2], bfrQ[2];
    loadB(0, 0, bfrP);          // prologue: kh=0 of k-tile-0 in flight
    if (USE_WS) {
        float p0 = pS[0][arow], q0 = qS[0][arow];
        stageSlot(0, 0, Als, p0, q0);
        stageSlot(0, 1, Als, p0, q0);
    } else {
        float p0 = pS[0][arow], q0 = qS[0][arow], r0 = rS[0][arow];
        stageSlotL(0, 0, Als, p0, q0, r0);
        stageSlotL(0, 1, Als, p0, q0, r0);
    }
    __syncthreads();

    for (int g = 0; g < NGRP; ++g) {
        __bf16* cur = Als + (g & 1) * AELEMS;
        __bf16* nxt = Als + ((g + 1) & 1) * AELEMS;
        const bool haveNext = (g + 1 < NGRP);

        float pC = 0.f, qC = 0.f, rC = 0.f;
        if (haveNext) {
            const int cn = (g + 1) >> 2;   // channel of next group's k-range
            pC = pS[cn][arow];
            qC = qS[cn][arow];
            if (!USE_WS) rC = rS[cn][arow];
        }

        #pragma unroll
        for (int sub = 0; sub < GRP; ++sub) {
            const int kt = g * GRP + sub;

            // kh=1 B for this k-tile (covered by stage/af below)
            loadB(kt, 1, bfrQ);

            // stage next group's A: slot1 during sub0, slot2 during sub2
            if (haveNext && sub == 0) {
                if (USE_WS) stageSlot(g + 1, 0, nxt, pC, qC);
                else        stageSlotL(g + 1, 0, nxt, pC, qC, rC);
            }
            if (haveNext && sub == 2) {
                if (USE_WS) stageSlot(g + 1, 1, nxt, pC, qC);
                else        stageSlotL(g + 1, 1, nxt, pC, qC, rC);
            }

            // A fragment reads: contiguous 1KB chunks, conflict-free
            const __bf16* Acur = cur + sub * (TM * TK);
            bf16x8 af[2][2];
            #pragma unroll
            for (int kh = 0; kh < 2; ++kh)
                #pragma unroll
                for (int mt = 0; mt < 2; ++mt)
                    af[kh][mt] = *(const bf16x8*)(Acur + (kh * 2 + mt) * 512 + lane * 8);

            // MFMA cluster 1: kh=0 with bfrP (issued one phase earlier)
            __builtin_amdgcn_s_setprio(1);
            #pragma unroll
            for (int mt = 0; mt < 2; ++mt)
                #pragma unroll
                for (int nt = 0; nt < 2; ++nt)
                    acc[mt][nt] = __builtin_amdgcn_mfma_f32_32x32x16_bf16(
                        af[0][mt], bfrP[nt], acc[mt][nt], 0, 0, 0);
            __builtin_amdgcn_s_setprio(0);

            // kh=0 B for the NEXT k-tile
            if (kt + 1 < NKT) loadB(kt + 1, 0, bfrP);

            // MFMA cluster 2: kh=1 with bfrQ
            __builtin_amdgcn_s_setprio(1);
            #pragma unroll
            for (int mt = 0; mt < 2; ++mt)
                #pragma unroll
                for (int nt = 0; nt < 2; ++nt)
                    acc[mt][nt] = __builtin_amdgcn_mfma_f32_32x32x16_bf16(
                        af[1][mt], bfrQ[nt], acc[mt][nt], 0, 0, 0);
            __builtin_amdgcn_s_setprio(0);
        }
        __syncthreads();      // one barrier per 4 k-tiles
    }

    // ---- fused epilogue: +mod_b, LayerNorm over 512 cols, gelu, store ----
    // 32x32 C layout: col = lane&31, row = (r&3) + 8*(r>>2) + 4*(lane>>5).
    float mbv[2], gv[2], bev[2];
    #pragma unroll
    for (int nt = 0; nt < 2; ++nt) {
        int col = wn * 64 + nt * 32 + (lane & 31);
        mbv[nt] = mod_b[col];
        gv[nt]  = mod_gamma[col];
        bev[nt] = mod_beta[col];
    }
    #pragma unroll
    for (int mt = 0; mt < 2; ++mt)
        #pragma unroll
        for (int nt = 0; nt < 2; ++nt)
            #pragma unroll
            for (int r = 0; r < 16; ++r)
                acc[mt][nt][r] += mbv[nt];

    // per-row partial sums within this wave's 64 cols (reduce over 32 lanes)
    #pragma unroll
    for (int mt = 0; mt < 2; ++mt) {
        #pragma unroll
        for (int r = 0; r < 16; ++r) {
            float y0 = acc[mt][0][r];
            float y1 = acc[mt][1][r];
            float s  = y0 + y1;
            float ss = fmaf(y0, y0, y1 * y1);
            #pragma unroll
            for (int off = 1; off < 32; off <<= 1) {
                s  += __shfl_xor(s,  off);
                ss += __shfl_xor(ss, off);
            }
            if ((lane & 31) == 0) {
                int row = mt * 32 + (r & 3) + ((r >> 2) << 3) + ((lane >> 5) << 2);
                redS[row][wn] = s;
                redQ[row][wn] = ss;
            }
        }
    }
    __syncthreads();
    if (tid < TM) {
        float s = 0.f, ss = 0.f;
        #pragma unroll
        for (int w = 0; w < 8; ++w) {
            s  += redS[tid][w];
            ss += redQ[tid][w];
        }
        const float inv_n = 1.0f / (float)H_DIM;
        float mu  = s * inv_n;
        float var = ss * inv_n - mu * mu;
        muS[tid]  = mu;
        invS[tid] = rsqrtf(var + EPS);
    }
    __syncthreads();

    #pragma unroll
    for (int mt = 0; mt < 2; ++mt) {
        #pragma unroll
        for (int r = 0; r < 16; ++r) {
            int row = mt * 32 + (r & 3) + ((r >> 2) << 3) + ((lane >> 5) << 2);
            float mu  = muS[row];
            float inv = invS[row];
            float* op = out + (size_t)(row0 + row) * H_DIM;
            #pragma unroll
            for (int nt = 0; nt < 2; ++nt) {
                int col = wn * 64 + nt * 32 + (lane & 31);
                float t = fmaf((acc[mt][nt][r] - mu) * inv, gv[nt], bev[nt]);
                op[col] = gelu_fast(t);
            }
        }
    }
}

extern "C" void kernel_launch(void* const* d_in, const int* in_sizes, int n_in,
                              void* d_out, int out_size, void* d_ws, size_t ws_size,
                              hipStream_t stream) {
    const float* x         = (const float*)d_in[0];
    const float* enc_w     = (const float*)d_in[1];
    const float* enc_b     = (const float*)d_in[2];
    const float* enc_gamma = (const float*)d_in[3];
    const float* enc_beta  = (const float*)d_in[4];
    const float* mod_w     = (const float*)d_in[5];
    const float* mod_b     = (const float*)d_in[6];
    const float* mod_gamma = (const float*)d_in[7];
    const float* mod_beta  = (const float*)d_in[8];
    float* out = (float*)d_out;

    const size_t wb_bytes = (size_t)H_DIM * K_DIM * sizeof(__bf16);   // 4 MB
    const size_t wf_off   = wb_bytes;
    const size_t bf_off   = wf_off + (size_t)C_CH * H_DIM * sizeof(float);  // +16 KB
    const size_t st_off   = bf_off + (size_t)C_CH * H_DIM * sizeof(float);  // +16 KB
    const size_t need     = st_off + (size_t)C_CH * 4 * sizeof(float);

    int use_ws = (ws_size >= need) ? 1 : 0;
    __bf16* Wb = (__bf16*)d_ws;
    float*  Wf = (float*)((char*)d_ws + wf_off);
    float*  Bf = (float*)((char*)d_ws + bf_off);
    float*  st = (float*)((char*)d_ws + st_off);

    if (use_ws) {
        prep_kernel<<<1024 + C_CH, 256, 0, stream>>>(
            mod_w, Wb, enc_w, enc_b, enc_gamma, Wf, Bf, st);
        fused_gemm_kernel<1><<<BS / TM, 512, 0, stream>>>(
            x, enc_w, enc_b, enc_gamma, enc_beta, mod_w, Wb, Wf, Bf, st,
            mod_b, mod_gamma, mod_beta, out);
    } else {
        fused_gemm_kernel<0><<<BS / TM, 512, 0, stream>>>(
            x, enc_w, enc_b, enc_gamma, enc_beta, mod_w, Wb,
            (const float*)0, (const float*)0, (const float*)0,
            mod_b, mod_gamma, mod_beta, out);
    }
}